// Round 9
// baseline (69.417 us; speedup 1.0000x reference)
//
#include <hip/hip_runtime.h>
#include <hip/hip_bf16.h>

#define VOCAB 50000
#define HID   256
#define BATCH 512
#define GH    768   // 3*H

typedef __attribute__((ext_vector_type(8))) __bf16 bf16x8;
typedef __attribute__((ext_vector_type(4))) float f32x4;
typedef __attribute__((ext_vector_type(4))) unsigned int u32x4;

union BFrag {
    bf16x8 v;
    u32x4  q;
    __bf16 b[8];
};

__device__ __forceinline__ float fast_sigmoid(float x) {
    return 1.0f / (1.0f + __expf(-x));
}
__device__ __forceinline__ float fast_tanh(float x) {
    return 1.0f - 2.0f / (1.0f + __expf(2.0f * x));
}

// 8 consecutive f32 -> one bf16x8 fragment via native casts.
__device__ __forceinline__ void cvt8(BFrag& t, f32x4 lo, f32x4 hi) {
    t.b[0] = (__bf16)lo.x; t.b[1] = (__bf16)lo.y;
    t.b[2] = (__bf16)lo.z; t.b[3] = (__bf16)lo.w;
    t.b[4] = (__bf16)hi.x; t.b[5] = (__bf16)hi.y;
    t.b[6] = (__bf16)hi.z; t.b[7] = (__bf16)hi.w;
}

// C[M x Ncols] = A[M x 256] @ Bm[Ncols x 256]^T   (K=256 whole, no K-loop)
// One block per 64-col tile (B fetched exactly once, XCD-proof). A streamed
// in 32-row chunks through DOUBLE-BUFFERED swizzled LDS (2 x 16KB):
//   chunk c:  ds_write buf^1 (data loaded at c-1)  ||  issue loads for c+2
//             ds_read buf + 16 MFMA + epilogue stores
//             lgkmcnt(0); s_barrier            <- single barrier per chunk
// The ds_write's vmcnt and the barrier's lgkm drain are both covered by a
// full chunk of latency; stores are never drained inside the loop.
// EPI 0: raw f32 store   1: tanh(acc + bias[col])
// ASRC 0: A f32 row-major  1: A bf16 row-major
// NTB 1: nontemporal B loads (B read exactly once)
template <int EPI, int ASRC, int NTB>
__global__ __launch_bounds__(256, 4) void gemm_db(
    const void* __restrict__ Asrc, const float* __restrict__ Bm,
    float* __restrict__ C, const float* __restrict__ bias,
    int Ncols, int mChunks)
{
    __shared__ char ldsA[2][32 * 512];        // 2 x (32 rows x 256 bf16), swizzled

    const int tid  = threadIdx.x;
    const int wid  = tid >> 6;
    const int lane = tid & 63;
    const int r    = lane & 15;
    const int g    = lane >> 4;
    const int col  = blockIdx.x * 64 + wid * 16 + r;
    const int bcol = col < Ncols ? col : (Ncols - 1);

    // ---- B fragments: 8 per wave, load + convert once, pin in regs ----
    BFrag bf[8];
    {
        const f32x4* wrow = reinterpret_cast<const f32x4*>(Bm + (size_t)bcol * 256);
        #pragma unroll
        for (int kk = 0; kk < 8; kk++) {
            f32x4 lo, hi;
            if (NTB) {
                lo = __builtin_nontemporal_load(&wrow[kk * 8 + g * 2]);
                hi = __builtin_nontemporal_load(&wrow[kk * 8 + g * 2 + 1]);
            } else {
                lo = wrow[kk * 8 + g * 2];
                hi = wrow[kk * 8 + g * 2 + 1];
            }
            cvt8(bf[kk], lo, hi);
        }
    }
    #pragma unroll
    for (int kk = 0; kk < 8; kk++)
        asm volatile("" : "+v"(bf[kk].q));    // keep resident (R5 lesson)
    float biasv = 0.0f;
    if (EPI == 1) biasv = bias[bcol];

    // ---- staging: one reg set, loads lead by 2 chunks, writes by 1 ----
    u32x4 areg[4];
    auto load_chunk = [&](int c) {
        const int mbase = (blockIdx.y * mChunks + c) * 32;
        if (ASRC == 1) {
            const u32x4* src = reinterpret_cast<const u32x4*>(
                (const unsigned short*)Asrc + (size_t)mbase * 256);
            #pragma unroll
            for (int i = 0; i < 4; i++) areg[i] = src[tid + i * 256];
        } else {
            const f32x4* src = reinterpret_cast<const f32x4*>(
                (const float*)Asrc + (size_t)mbase * 256);
            #pragma unroll
            for (int i = 0; i < 4; i++) {
                int u = tid + i * 256;
                BFrag t; cvt8(t, src[2 * u], src[2 * u + 1]);
                areg[i] = t.q;
            }
        }
    };
    auto write_lds = [&](int buf) {
        #pragma unroll
        for (int i = 0; i < 4; i++) {
            int u = tid + i * 256;            // 0..1023 16B units
            int row = u >> 5, j = u & 31;
            int byte = row * 512 + ((j ^ (row & 7)) << 4);
            *reinterpret_cast<u32x4*>(&ldsA[buf][byte]) = areg[i];
        }
    };

    // prologue: buf0 <- chunk0; areg <- chunk1
    load_chunk(0);
    write_lds(0);
    if (mChunks > 1) load_chunk(1);
    asm volatile("s_waitcnt lgkmcnt(0)\n\ts_barrier" ::: "memory");

    for (int c = 0; c < mChunks; c++) {
        const int cur = c & 1;
        if (c + 1 < mChunks) {
            write_lds(cur ^ 1);               // stage c+1 (regs from c-1)
            if (c + 2 < mChunks) load_chunk(c + 2);
        }

        f32x4 acc[2];
        acc[0] = (f32x4){0.f, 0.f, 0.f, 0.f};
        acc[1] = (f32x4){0.f, 0.f, 0.f, 0.f};

        #pragma unroll
        for (int kk = 0; kk < 8; kk++) {
            #pragma unroll
            for (int m = 0; m < 2; m++) {
                int arow = m * 16 + r;
                int byte = arow * 512 + (((kk * 4 + g) ^ (arow & 7)) << 4);
                BFrag a;
                a.q = *reinterpret_cast<const u32x4*>(&ldsA[cur][byte]);
                acc[m] = __builtin_amdgcn_mfma_f32_16x16x32_bf16(a.v, bf[kk].v, acc[m], 0, 0, 0);
            }
        }

        if (col < Ncols) {
            const int rowbase = (blockIdx.y * mChunks + c) * 32 + g * 4;
            #pragma unroll
            for (int m = 0; m < 2; m++) {
                #pragma unroll
                for (int j = 0; j < 4; j++) {
                    float v = acc[m][j];
                    if (EPI == 1) v = fast_tanh(v + biasv);
                    C[(size_t)(rowbase + m * 16 + j) * Ncols + col] = v;
                }
            }
        }

        if (c + 1 < mChunks)                  // writes visible + reads retired
            asm volatile("s_waitcnt lgkmcnt(0)\n\ts_barrier" ::: "memory");
    }
}

// K2: GRU gates. One block per batch row, thread = k. Writes h1 (f32, d_out
// tail) and h1 bf16 row-major (K3's A operand).
__global__ __launch_bounds__(256) void gru_gate(
    const int* __restrict__ inp, const float* __restrict__ hidden,
    const float* __restrict__ w_ih, const float* __restrict__ b_ih,
    const float* __restrict__ b_hh, const float* __restrict__ hproj,
    float* __restrict__ h1out, unsigned short* __restrict__ h1bf)
{
    const int b = blockIdx.x;
    const int k = threadIdx.x;
    const int c = inp[b];

    float xr = w_ih[(size_t)k * VOCAB + c]         + b_ih[k];
    float xz = w_ih[(size_t)(k + 256) * VOCAB + c] + b_ih[k + 256];
    float xn = w_ih[(size_t)(k + 512) * VOCAB + c] + b_ih[k + 512];

    float hr = hproj[b * GH + k]       + b_hh[k];
    float hz = hproj[b * GH + 256 + k] + b_hh[k + 256];
    float hn = hproj[b * GH + 512 + k] + b_hh[k + 512];

    float rg = fast_sigmoid(xr + hr);
    float zg = fast_sigmoid(xz + hz);
    float ng = fast_tanh(xn + rg * hn);
    float h0 = hidden[b * HID + k];
    float h1 = (1.0f - zg) * ng + zg * h0;

    h1out[b * HID + k] = h1;
    __bf16 hb = (__bf16)h1;
    h1bf[b * HID + k] = __builtin_bit_cast(unsigned short, hb);
}

extern "C" void kernel_launch(void* const* d_in, const int* in_sizes, int n_in,
                              void* d_out, int out_size, void* d_ws, size_t ws_size,
                              hipStream_t stream) {
    const int*   input  = (const int*)  d_in[0];
    // d_in[1] = target (unused)
    const float* hidden = (const float*)d_in[2];
    const float* w_ih   = (const float*)d_in[3];
    const float* w_hh   = (const float*)d_in[4];
    const float* b_ih   = (const float*)d_in[5];
    const float* b_hh   = (const float*)d_in[6];
    const float* w_out  = (const float*)d_in[7];
    const float* b_out  = (const float*)d_in[8];

    float* logit = (float*)d_out;                            // [512, 50000]
    float* h1    = (float*)d_out + (size_t)BATCH * VOCAB;    // [512, 256]

    float*          hproj = (float*)d_ws;                                   // 1.5 MB
    unsigned short* h1bf  = (unsigned short*)((char*)d_ws + (size_t)BATCH * GH * 4);

    // K1: hproj = h0 @ w_hh^T  (512 x 768) — 192 one-chunk blocks (latency)
    dim3 g1(GH / 64, BATCH / 32);           // (12, 16), mChunks = 1
    gemm_db<0, 0, 0><<<g1, 256, 0, stream>>>(hidden, w_hh, hproj, nullptr, GH, 1);

    // K2: gates -> h1 (f32) + h1bf (row-major bf16)
    gru_gate<<<BATCH, 256, 0, stream>>>(input, hidden, w_ih, b_ih, b_hh, hproj,
                                        h1, h1bf);

    // K3: logit = tanh(h1 @ w_out^T + b_out) — 782 col-tile blocks, 16 chunks
    dim3 g3((VOCAB + 63) / 64, 1);
    gemm_db<1, 1, 1><<<g3, 256, 0, stream>>>(h1bf, w_out, logit, b_out, VOCAB, 16);
}